// Round 3
// baseline (1462.424 us; speedup 1.0000x reference)
//
#include <hip/hip_runtime.h>
#include <cstdint>
#include <cstddef>

#define HH 512
#define WW 512
#define CPN 32
#define PLANE_ELEMS (CPN * HH * WW)   // 8388608
#define SYT (WW * CPN)                // 16384: y-stride in transposed [H,W,C] plane
#define NTILE (3 * 512 * 8)           // plane-transpose tile units

// ---------------------------------------------------------------------------
// Single-dispatch persistent kernel: W1 transpose + plane transpose
// (CHW->HWC) + device-wide software barrier + fused sample/product/MLP.
// Grid is sized by the OCCUPANCY API on the host (co-residency guaranteed on
// any partition); the barrier spin has a wall-clock timeout so a residency
// violation degrades to a wrong answer instead of a GPU hang.
// ---------------------------------------------------------------------------
__global__ __launch_bounds__(256, 3) void kp_main(
    const float* __restrict__ coords,
    const float* __restrict__ p0, const float* __restrict__ p1,
    const float* __restrict__ p2,
    const float* __restrict__ W1, const float* __restrict__ b1,
    const float* __restrict__ W2, const float* __restrict__ b2,
    float* __restrict__ out, int P,
    unsigned int* __restrict__ bar, float* __restrict__ W1t,
    float* __restrict__ tr)
{
    __shared__ float feats[256][33];   // 33.8 KB; +1 pad -> conflict-free phase-2 reads
    int t  = threadIdx.x;
    int nb = gridDim.x;

    // ---- phase A0: transpose W1 [32][128] -> W1t [128][32] (block 0 only)
    if (blockIdx.x == 0) {
        for (int idx = t; idx < 4096; idx += 256) {
            int j = idx >> 5, k = idx & 31;
            W1t[idx] = W1[k * 128 + j];
        }
    }

    // ---- phase A: plane transpose [C,H,W] -> [H,W,C], grid-stride
    {
        float (*tile)[65] = reinterpret_cast<float (*)[65]>(&feats[0][0]); // 8.3 KB alias
        for (int bid = blockIdx.x; bid < NTILE; bid += nb) {
            int xb = bid & 7, y = (bid >> 3) & 511, pl = bid >> 12;
            const float* src = (pl == 0) ? p0 : ((pl == 1) ? p1 : p2);
            int xbase = xb * 64;
            int x = t & 63, cq = t >> 6;
            __syncthreads();                       // protect tile reuse across iters
#pragma unroll
            for (int i = 0; i < 8; ++i) {
                int c = cq * 8 + i;
                tile[c][x] = src[c * (HH * WW) + y * WW + xbase + x];
            }
            __syncthreads();
            int c2 = t & 31, xq = t >> 5;
            float* dst = tr + (size_t)pl * PLANE_ELEMS + ((size_t)y * WW + xbase) * CPN;
#pragma unroll
            for (int i = 0; i < 8; ++i) {
                int xx = xq * 8 + i;
                dst[xx * CPN + c2] = tile[c2][xx];
            }
        }
    }

    // ---- device-wide barrier (co-residency via occupancy-sized grid;
    //      timeout escape prevents infinite hang if that ever fails)
    __syncthreads();
    if (t == 0) {
        __threadfence();   // release tr / W1t writes (agent scope)
        __hip_atomic_fetch_add(bar, 1u, __ATOMIC_ACQ_REL, __HIP_MEMORY_SCOPE_AGENT);
        long long t0 = wall_clock64();             // ~100 MHz constant clock
        while (__hip_atomic_load(bar, __ATOMIC_ACQUIRE, __HIP_MEMORY_SCOPE_AGENT)
               < (unsigned)nb) {
            __builtin_amdgcn_s_sleep(8);
            if (wall_clock64() - t0 > 50000000LL) break;   // ~0.5 s escape hatch
        }
        __threadfence();   // acquire
    }
    __syncthreads();

    // ---- phase B: gather + feature product + MLP, grid-stride over point blocks
    int wave = t >> 6, lane = t & 63, c = lane & 31, xsel = lane >> 5;
    const float* pa  = tr;
    const float* pbp = tr + PLANE_ELEMS;
    const float* pcp = tr + 2 * PLANE_ELEMS;
    int nPB = (P + 255) >> 8;

    for (int pbk = blockIdx.x; pbk < nPB; pbk += nb) {
        int pbase = pbk << 8;
        __syncthreads();                           // prev iter's feats reads done
        for (int i = 0; i < 64; ++i) {
            int p = pbase + i * 4 + wave;          // wave-uniform
            if (p < P) {
                float cx = coords[3 * p + 0];
                float cy = coords[3 * p + 1];
                float cz = coords[3 * p + 2];
                float f = 1.0f;
#pragma unroll
                for (int pl = 0; pl < 3; ++pl) {
                    const float* plane = (pl == 0) ? pa : ((pl == 1) ? pbp : pcp);
                    float u = (pl == 1) ? cy : cx;   // -> W axis
                    float v = (pl == 0) ? cy : cz;   // -> H axis
                    float xf = (u + 1.0f) * (0.5f * 511.0f);
                    float yf = (v + 1.0f) * (0.5f * 511.0f);
                    float x0f = floorf(xf), y0f = floorf(yf);
                    float wx = xf - x0f, wy = yf - y0f;
                    int x0 = (int)x0f, y0 = (int)y0f;
                    x0 = min(max(x0, 0), 510);
                    y0 = min(max(y0, 0), 510);
                    const float* bp = plane + (size_t)y0 * SYT +
                                      (size_t)(x0 + xsel) * CPN + c;
                    float v0 = bp[0];                // row y0 (256B coalesced / wave)
                    float v1 = bp[SYT];              // row y0+1
                    float wxl = xsel ? wx : (1.0f - wx);
                    float s = (v0 * (1.0f - wy) + v1 * wy) * wxl;
                    s += __shfl_xor(s, 32, 64);      // combine x0/x1 halves
                    f *= s;
                }
                if (xsel == 0) feats[i * 4 + wave][c] = fmaxf(f, 0.0f);
            }
        }
        __syncthreads();
        int p = pbase + t;
        if (p < P) {
            float fr[32];
#pragma unroll
            for (int k = 0; k < 32; ++k) fr[k] = feats[t][k];
            float acc = b2[0];
#pragma unroll 4
            for (int j = 0; j < 128; ++j) {
                float a = b1[j];
#pragma unroll
                for (int k = 0; k < 32; ++k) a += fr[k] * W1t[j * 32 + k];
                acc += fmaxf(a, 0.0f) * W2[j];
            }
            out[p] = acc;
        }
    }
}

// ---------------------------------------------------------------------------
// Fallback (only if ws_size too small): direct CHW sampling, no workspace.
// ---------------------------------------------------------------------------
__global__ __launch_bounds__(256) void kp_direct(
    const float* __restrict__ coords,
    const float* __restrict__ p0, const float* __restrict__ p1,
    const float* __restrict__ p2,
    const float* __restrict__ W1, const float* __restrict__ b1,
    const float* __restrict__ W2, const float* __restrict__ b2,
    float* __restrict__ out, int P)
{
    __shared__ float feats[256][33];
    int t = threadIdx.x;
    int wave = t >> 6, lane = t & 63, c = lane & 31, xsel = lane >> 5;
    int pbase = blockIdx.x * 256;

    for (int i = 0; i < 64; ++i) {
        int p = pbase + i * 4 + wave;
        if (p < P) {
            float cx = coords[3 * p + 0];
            float cy = coords[3 * p + 1];
            float cz = coords[3 * p + 2];
            float f = 1.0f;
#pragma unroll
            for (int pl = 0; pl < 3; ++pl) {
                const float* plane = (pl == 0) ? p0 : ((pl == 1) ? p1 : p2);
                float u = (pl == 1) ? cy : cx;
                float v = (pl == 0) ? cy : cz;
                float xf = (u + 1.0f) * (0.5f * 511.0f);
                float yf = (v + 1.0f) * (0.5f * 511.0f);
                float x0f = floorf(xf), y0f = floorf(yf);
                float wx = xf - x0f, wy = yf - y0f;
                int x0 = (int)x0f, y0 = (int)y0f;
                x0 = min(max(x0, 0), 510);
                y0 = min(max(y0, 0), 510);
                const float* bp = plane + (size_t)c * (HH * WW) +
                                  (size_t)y0 * WW + (x0 + xsel);
                float v0 = bp[0];
                float v1 = bp[WW];
                float wxl = xsel ? wx : (1.0f - wx);
                float s = (v0 * (1.0f - wy) + v1 * wy) * wxl;
                s += __shfl_xor(s, 32, 64);
                f *= s;
            }
            if (xsel == 0) feats[i * 4 + wave][c] = fmaxf(f, 0.0f);
        }
    }
    __syncthreads();
    int p = pbase + t;
    if (p < P) {
        float fr[32];
#pragma unroll
        for (int k = 0; k < 32; ++k) fr[k] = feats[t][k];
        float acc = b2[0];
#pragma unroll 4
        for (int j = 0; j < 128; ++j) {
            float a = b1[j];
#pragma unroll
            for (int k = 0; k < 32; ++k) a += fr[k] * W1[k * 128 + j];
            acc += fmaxf(a, 0.0f) * W2[j];
        }
        out[p] = acc;
    }
}

// ---------------------------------------------------------------------------
extern "C" void kernel_launch(void* const* d_in, const int* in_sizes, int n_in,
                              void* d_out, int out_size, void* d_ws, size_t ws_size,
                              hipStream_t stream) {
    const float* coords = (const float*)d_in[0];
    const float* p0 = (const float*)d_in[1];
    const float* p1 = (const float*)d_in[2];
    const float* p2 = (const float*)d_in[3];
    const float* W1 = (const float*)d_in[4];
    const float* b1 = (const float*)d_in[5];
    const float* W2 = (const float*)d_in[6];
    const float* b2 = (const float*)d_in[7];
    float* out = (float*)d_out;
    int P = in_sizes[0] / 3;   // 2,000,000

    // ws layout: [0..255] barrier counter | W1t (16KB) | tr planes (96MB)
    const size_t w1t_off = 256;
    const size_t tr_off  = 256 + 4096 * sizeof(float);          // 64B-aligned
    const size_t need    = tr_off + (size_t)3 * PLANE_ELEMS * sizeof(float);

    if (ws_size >= need) {
        // Deterministic, capture-safe occupancy-derived grid: guaranteed
        // co-residency on any partition size.
        int dev = 0, nCU = 0, maxb = 0;
        hipGetDevice(&dev);
        hipDeviceGetAttribute(&nCU, hipDeviceAttributeMultiprocessorCount, dev);
        hipOccupancyMaxActiveBlocksPerMultiprocessor(&maxb, kp_main, 256, 0);
        if (nCU <= 0) nCU = 32;
        if (maxb <= 0) maxb = 1;
        int nblk = nCU * maxb;

        unsigned int* bar = (unsigned int*)d_ws;
        float* W1t = (float*)((char*)d_ws + w1t_off);
        float* tr  = (float*)((char*)d_ws + tr_off);
        hipMemsetAsync(d_ws, 0, 256, stream);    // reset barrier counter (in-graph)
        kp_main<<<dim3(nblk), dim3(256), 0, stream>>>(
            coords, p0, p1, p2, W1, b1, W2, b2, out, P, bar, W1t, tr);
    } else {
        int nblk = (P + 255) / 256;
        kp_direct<<<dim3(nblk), dim3(256), 0, stream>>>(
            coords, p0, p1, p2, W1, b1, W2, b2, out, P);
    }
}

// Round 4
// 1243.409 us; speedup vs baseline: 1.1761x; 1.1761x over previous
//
#include <hip/hip_runtime.h>
#include <hip/hip_fp16.h>
#include <cstdint>
#include <cstddef>

#define HH 512
#define WW 512
#define CPN 32
#define PLANE_H2 (512 * 512 * 16)     // half2 elements per transposed plane
#define NTILE (3 * 512 * 8)           // plane-transpose tile units

// ---------------------------------------------------------------------------
// Single-dispatch persistent kernel:
//   A0: W1 [32][128] -> W1t [128][32] (fp32)
//   A : planes [C,H,W] fp32 -> tr [H,W,C] fp16 (half2-packed, c fastest)
//   device-wide software barrier (occupancy-sized grid + timeout escape)
//   B : per 256-pt chunk: coords->LDS, gather (lane = point-quad x ch-pair,
//       4 fp16 corners per lane, in-register bilinear, no shuffles),
//       feats->LDS, thread-per-point fp32 MLP.
// ---------------------------------------------------------------------------
__global__ __launch_bounds__(256, 4) void kp_main(
    const float* __restrict__ coords,
    const float* __restrict__ p0, const float* __restrict__ p1,
    const float* __restrict__ p2,
    const float* __restrict__ W1, const float* __restrict__ b1,
    const float* __restrict__ W2, const float* __restrict__ b2,
    float* __restrict__ out, int P,
    unsigned int* __restrict__ bar, float* __restrict__ W1t,
    __half2* __restrict__ tr)
{
    __shared__ float feats[256][33];   // 33792 B; +1 pad -> phase-2 conflict-free
    __shared__ float cbuf[768];        // 3072 B: 256 pts x 3 coords
    int t  = threadIdx.x;
    int nb = gridDim.x;

    // ---- phase A0: W1 transpose (block 0)
    if (blockIdx.x == 0) {
        for (int idx = t; idx < 4096; idx += 256) {
            int j = idx >> 5, k = idx & 31;
            W1t[idx] = W1[k * 128 + j];
        }
    }

    // ---- phase A: planes [C,H,W] fp32 -> [H,W,C] fp16, grid-stride
    {
        float (*tile)[65] = reinterpret_cast<float (*)[65]>(&feats[0][0]); // 8.3 KB alias
        for (int bid = blockIdx.x; bid < NTILE; bid += nb) {
            int xb = bid & 7, y = (bid >> 3) & 511, pl = bid >> 12;
            const float* src = (pl == 0) ? p0 : ((pl == 1) ? p1 : p2);
            int xbase = xb * 64;
            __syncthreads();                       // tile reuse across iters
            int x = t & 63, cq = t >> 6;
#pragma unroll
            for (int i = 0; i < 8; ++i) {
                int c = cq * 8 + i;
                tile[c][x] = src[c * (HH * WW) + y * WW + xbase + x];
            }
            __syncthreads();
            int c2 = t & 15, xq = t >> 4;          // ch-pair, x-slot
            __half2* dst = tr + (size_t)pl * PLANE_H2 + ((size_t)y * WW + xbase) * 16;
#pragma unroll
            for (int i = 0; i < 4; ++i) {
                int xx = xq * 4 + i;
                dst[xx * 16 + c2] =
                    __floats2half2_rn(tile[2 * c2][xx], tile[2 * c2 + 1][xx]);
            }
        }
    }

    // ---- device-wide barrier (co-residency via occupancy-sized grid)
    __syncthreads();
    if (t == 0) {
        __threadfence();   // release tr / W1t
        __hip_atomic_fetch_add(bar, 1u, __ATOMIC_ACQ_REL, __HIP_MEMORY_SCOPE_AGENT);
        long long t0 = wall_clock64();
        while (__hip_atomic_load(bar, __ATOMIC_ACQUIRE, __HIP_MEMORY_SCOPE_AGENT)
               < (unsigned)nb) {
            __builtin_amdgcn_s_sleep(8);
            if (wall_clock64() - t0 > 50000000LL) break;   // ~0.5 s escape hatch
        }
        __threadfence();   // acquire
    }
    __syncthreads();

    // ---- phase B
    int wave = t >> 6, lane = t & 63;
    int grp  = lane >> 4;              // point within quad (0..3)
    int c2   = lane & 15;              // channel pair (0..15)
    const __half2* pla = tr;
    const __half2* plb = tr + PLANE_H2;
    const __half2* plc = tr + 2 * PLANE_H2;
    int nPB = (P + 255) >> 8;
    int P3  = P * 3;

    for (int pbk = blockIdx.x; pbk < nPB; pbk += nb) {
        int pbase = pbk << 8;
        __syncthreads();                           // cbuf/feats reuse safe
        // stage 256 points' coords (coalesced)
#pragma unroll
        for (int r = 0; r < 3; ++r) {
            int idx = r * 256 + t;
            int g   = pbase * 3 + idx;
            cbuf[idx] = (g < P3) ? coords[g] : 0.0f;
        }
        __syncthreads();

        // gather: each wave covers 64 points in quads of 4
#pragma unroll 2
        for (int i = 0; i < 16; ++i) {
            int pi = wave * 64 + i * 4 + grp;      // 0..255
            float cx = cbuf[pi * 3 + 0];
            float cy = cbuf[pi * 3 + 1];
            float cz = cbuf[pi * 3 + 2];
            float a0 = 1.0f, a1 = 1.0f;
#pragma unroll
            for (int pl = 0; pl < 3; ++pl) {
                const __half2* pp = (pl == 0) ? pla : ((pl == 1) ? plb : plc);
                float u = (pl == 1) ? cy : cx;     // -> W axis
                float v = (pl == 0) ? cy : cz;     // -> H axis
                float xf = (u + 1.0f) * (0.5f * 511.0f);
                float yf = (v + 1.0f) * (0.5f * 511.0f);
                float x0f = floorf(xf), y0f = floorf(yf);
                float wx = xf - x0f, wy = yf - y0f;
                int x0 = min(max((int)x0f, 0), 510);
                int y0 = min(max((int)y0f, 0), 510);
                const __half2* bp = pp + ((size_t)y0 * WW + x0) * 16 + c2;
                __half2 h00 = bp[0];               // (y0 , x0)
                __half2 h01 = bp[16];              // (y0 , x0+1)
                __half2 h10 = bp[WW * 16];         // (y0+1, x0)
                __half2 h11 = bp[WW * 16 + 16];    // (y0+1, x0+1)
                float w11 = wx * wy;
                float w01 = wx - w11;              // wx*(1-wy)
                float w10 = wy - w11;              // (1-wx)*wy
                float w00 = 1.0f - wx - w10;       // (1-wx)*(1-wy)
                float2 f00 = __half22float2(h00);
                float2 f01 = __half22float2(h01);
                float2 f10 = __half22float2(h10);
                float2 f11 = __half22float2(h11);
                float s0 = f00.x * w00 + f01.x * w01 + f10.x * w10 + f11.x * w11;
                float s1 = f00.y * w00 + f01.y * w01 + f10.y * w10 + f11.y * w11;
                a0 *= s0; a1 *= s1;
            }
            if (pbase + pi < P) {
                feats[pi][2 * c2]     = fmaxf(a0, 0.0f);
                feats[pi][2 * c2 + 1] = fmaxf(a1, 0.0f);
            }
        }
        __syncthreads();

        // MLP: thread-per-point
        int p = pbase + t;
        if (p < P) {
            float fr[32];
#pragma unroll
            for (int k = 0; k < 32; ++k) fr[k] = feats[t][k];
            float acc = b2[0];
#pragma unroll 4
            for (int j = 0; j < 128; ++j) {
                float a = b1[j];
#pragma unroll
                for (int k = 0; k < 32; ++k) a += fr[k] * W1t[j * 32 + k];
                acc += fmaxf(a, 0.0f) * W2[j];
            }
            out[p] = acc;
        }
    }
}

// ---------------------------------------------------------------------------
// Fallback (ws too small): direct CHW fp32 sampling, no workspace.
// ---------------------------------------------------------------------------
__global__ __launch_bounds__(256) void kp_direct(
    const float* __restrict__ coords,
    const float* __restrict__ p0, const float* __restrict__ p1,
    const float* __restrict__ p2,
    const float* __restrict__ W1, const float* __restrict__ b1,
    const float* __restrict__ W2, const float* __restrict__ b2,
    float* __restrict__ out, int P)
{
    __shared__ float feats[256][33];
    int t = threadIdx.x;
    int wave = t >> 6, lane = t & 63, c = lane & 31, xsel = lane >> 5;
    int pbase = blockIdx.x * 256;

    for (int i = 0; i < 64; ++i) {
        int p = pbase + i * 4 + wave;
        if (p < P) {
            float cx = coords[3 * p + 0];
            float cy = coords[3 * p + 1];
            float cz = coords[3 * p + 2];
            float f = 1.0f;
#pragma unroll
            for (int pl = 0; pl < 3; ++pl) {
                const float* plane = (pl == 0) ? p0 : ((pl == 1) ? p1 : p2);
                float u = (pl == 1) ? cy : cx;
                float v = (pl == 0) ? cy : cz;
                float xf = (u + 1.0f) * (0.5f * 511.0f);
                float yf = (v + 1.0f) * (0.5f * 511.0f);
                float x0f = floorf(xf), y0f = floorf(yf);
                float wx = xf - x0f, wy = yf - y0f;
                int x0 = min(max((int)x0f, 0), 510);
                int y0 = min(max((int)y0f, 0), 510);
                const float* bp = plane + (size_t)c * (HH * WW) +
                                  (size_t)y0 * WW + (x0 + xsel);
                float v0 = bp[0];
                float v1 = bp[WW];
                float wxl = xsel ? wx : (1.0f - wx);
                float s = (v0 * (1.0f - wy) + v1 * wy) * wxl;
                s += __shfl_xor(s, 32, 64);
                f *= s;
            }
            if (xsel == 0) feats[i * 4 + wave][c] = fmaxf(f, 0.0f);
        }
    }
    __syncthreads();
    int p = pbase + t;
    if (p < P) {
        float fr[32];
#pragma unroll
        for (int k = 0; k < 32; ++k) fr[k] = feats[t][k];
        float acc = b2[0];
#pragma unroll 4
        for (int j = 0; j < 128; ++j) {
            float a = b1[j];
#pragma unroll
            for (int k = 0; k < 32; ++k) a += fr[k] * W1[k * 128 + j];
            acc += fmaxf(a, 0.0f) * W2[j];
        }
        out[p] = acc;
    }
}

// ---------------------------------------------------------------------------
extern "C" void kernel_launch(void* const* d_in, const int* in_sizes, int n_in,
                              void* d_out, int out_size, void* d_ws, size_t ws_size,
                              hipStream_t stream) {
    const float* coords = (const float*)d_in[0];
    const float* p0 = (const float*)d_in[1];
    const float* p1 = (const float*)d_in[2];
    const float* p2 = (const float*)d_in[3];
    const float* W1 = (const float*)d_in[4];
    const float* b1 = (const float*)d_in[5];
    const float* W2 = (const float*)d_in[6];
    const float* b2 = (const float*)d_in[7];
    float* out = (float*)d_out;
    int P = in_sizes[0] / 3;   // 2,000,000

    // ws layout: [0..255] barrier | W1t 16KB | tr planes (3 x 16MB fp16)
    const size_t w1t_off = 256;
    const size_t tr_off  = 256 + 4096 * sizeof(float);
    const size_t need    = tr_off + (size_t)3 * PLANE_H2 * sizeof(__half2);

    if (ws_size >= need) {
        int dev = 0, nCU = 0, maxb = 0;
        hipGetDevice(&dev);
        hipDeviceGetAttribute(&nCU, hipDeviceAttributeMultiprocessorCount, dev);
        hipOccupancyMaxActiveBlocksPerMultiprocessor(&maxb, kp_main, 256, 0);
        if (nCU <= 0) nCU = 32;
        if (maxb <= 0) maxb = 1;
        int nblk = nCU * maxb;

        unsigned int* bar = (unsigned int*)d_ws;
        float* W1t = (float*)((char*)d_ws + w1t_off);
        __half2* tr = (__half2*)((char*)d_ws + tr_off);
        hipMemsetAsync(d_ws, 0, 256, stream);    // reset barrier counter (in-graph)
        kp_main<<<dim3(nblk), dim3(256), 0, stream>>>(
            coords, p0, p1, p2, W1, b1, W2, b2, out, P, bar, W1t, tr);
    } else {
        int nblk = (P + 255) / 256;
        kp_direct<<<dim3(nblk), dim3(256), 0, stream>>>(
            coords, p0, p1, p2, W1, b1, W2, b2, out, P);
    }
}

// Round 5
// 718.368 us; speedup vs baseline: 2.0358x; 1.7309x over previous
//
#include <hip/hip_runtime.h>
#include <hip/hip_fp16.h>
#include <cstdint>
#include <cstddef>

#define HH 512
#define WW 512
#define PLANE_H2 (512 * 512 * 16)     // half2 elements per transposed plane
#define NTILE (3 * 512 * 8)           // plane-transpose tile units

typedef _Float16 f16x8 __attribute__((ext_vector_type(8)));
typedef float    f32x4 __attribute__((ext_vector_type(4)));

// ---------------------------------------------------------------------------
// Single-dispatch persistent kernel.
//   A : planes [C,H,W] fp32 -> tr [H,W,C] fp16 (c fastest, 64B per cell)
//   (W1 -> LDS fp16 [128][40], per block, pre-barrier)
//   device-wide software barrier (occupancy-sized grid + timeout escape)
//   B : per wave, 16 points/group, barrier-free:
//       lane=(kblock,point): 12x 16B corner loads -> fp32 bilinear+product
//       -> feats already in MFMA A-frag layout -> 8x mfma 16x16x32_f16
//       -> relu/W2 partials -> shfl_xor reduce -> dwordx4 store.
// ---------------------------------------------------------------------------
__global__ __launch_bounds__(256, 6) void kp_main(
    const float* __restrict__ coords,
    const float* __restrict__ p0, const float* __restrict__ p1,
    const float* __restrict__ p2,
    const float* __restrict__ W1, const float* __restrict__ b1,
    const float* __restrict__ W2, const float* __restrict__ b2,
    float* __restrict__ out, int P,
    unsigned int* __restrict__ bar, __half2* __restrict__ tr)
{
    __shared__ float    tileF[32][65];   // 8.32 KB (transpose phase only)
    __shared__ _Float16 W1h[128][40];    // 10.24 KB, [j][k] padded: 16B-aligned rows
    int t  = threadIdx.x;
    int nb = gridDim.x;

    // ---- phase A: planes [C,H,W] fp32 -> [H,W,C] fp16, grid-stride
    for (int bid = blockIdx.x; bid < NTILE; bid += nb) {
        int xb = bid & 7, y = (bid >> 3) & 511, pl = bid >> 12;
        const float* src = (pl == 0) ? p0 : ((pl == 1) ? p1 : p2);
        int xbase = xb * 64;
        __syncthreads();                       // tile reuse across iters
        int x = t & 63, cq = t >> 6;
#pragma unroll
        for (int i = 0; i < 8; ++i) {
            int c = cq * 8 + i;
            tileF[c][x] = src[c * (HH * WW) + y * WW + xbase + x];
        }
        __syncthreads();
        int c2 = t & 15, xq = t >> 4;          // ch-pair, x-slot
        __half2* dst = tr + (size_t)pl * PLANE_H2 + ((size_t)y * WW + xbase) * 16;
#pragma unroll
        for (int i = 0; i < 4; ++i) {
            int xx = xq * 4 + i;
            dst[xx * 16 + c2] =
                __floats2half2_rn(tileF[2 * c2][xx], tileF[2 * c2 + 1][xx]);
        }
    }

    // ---- W1 -> LDS fp16 (per block; visibility via barrier's __syncthreads)
    for (int e = t; e < 4096; e += 256) {
        int j = e >> 5, k = e & 31;
        W1h[j][k] = (_Float16)W1[k * 128 + j];
    }

    // ---- device-wide barrier
    __syncthreads();
    if (t == 0) {
        __threadfence();   // release tr
        __hip_atomic_fetch_add(bar, 1u, __ATOMIC_ACQ_REL, __HIP_MEMORY_SCOPE_AGENT);
        long long t0 = wall_clock64();
        while (__hip_atomic_load(bar, __ATOMIC_ACQUIRE, __HIP_MEMORY_SCOPE_AGENT)
               < (unsigned)nb) {
            __builtin_amdgcn_s_sleep(8);
            if (wall_clock64() - t0 > 50000000LL) break;   // ~0.5 s escape hatch
        }
        __threadfence();   // acquire
    }
    __syncthreads();       // also makes W1h visible block-wide

    // ---- phase B: barrier-free per-wave loop over 16-point groups
    int wave = t >> 6, lane = t & 63;
    int pl15 = lane & 15;              // point-in-group AND j-lane AND D-col
    int kb   = lane >> 4;              // k-block (channels kb*8..kb*8+7), D row group
    const char* trb = (const char*)tr;

    // per-lane epilogue constants
    float b1r[8], w2r[8];
#pragma unroll
    for (int nt = 0; nt < 8; ++nt) {
        b1r[nt] = b1[16 * nt + pl15];
        w2r[nt] = W2[16 * nt + pl15];
    }
    float b2v = b2[0];

    int wid = blockIdx.x * 4 + wave;
    int nw  = nb * 4;
    int nG  = (P + 15) >> 4;

    for (int g = wid; g < nG; g += nw) {
        int pbase = g << 4;
        int pc = min(pbase + pl15, P - 1);
        // 16B load covering this point's 3 coords (4B-aligned OK; allocations
        // are page-padded so the 4B overread at p=P-1 is safe)
        float4 cc = *(const float4*)(coords + (size_t)pc * 3);
        float cx = cc.x, cy = cc.y, cz = cc.z;

        float s[8];
#pragma unroll
        for (int pl = 0; pl < 3; ++pl) {
            float u = (pl == 1) ? cy : cx;     // -> W axis
            float v = (pl == 0) ? cy : cz;     // -> H axis
            float xf = (u + 1.0f) * (0.5f * 511.0f);
            float yf = (v + 1.0f) * (0.5f * 511.0f);
            float x0f = floorf(xf), y0f = floorf(yf);
            float wx = xf - x0f, wy = yf - y0f;
            int x0 = min(max((int)x0f, 0), 510);
            int y0 = min(max((int)y0f, 0), 510);
            const char* bp = trb + ((size_t)pl * PLANE_H2) * 4 +
                             ((size_t)(y0 * WW + x0) * 64 + kb * 16);
            f16x8 q00 = *(const f16x8*)(bp);
            f16x8 q01 = *(const f16x8*)(bp + 64);
            f16x8 q10 = *(const f16x8*)(bp + WW * 64);
            f16x8 q11 = *(const f16x8*)(bp + WW * 64 + 64);
            float w11 = wx * wy;
            float w01 = wx - w11;              // wx*(1-wy)
            float w10 = wy - w11;              // (1-wx)*wy
            float w00 = 1.0f - wx - w10;       // (1-wx)*(1-wy)
#pragma unroll
            for (int e = 0; e < 8; ++e) {
                float smp = (float)q00[e] * w00 + (float)q01[e] * w01 +
                            (float)q10[e] * w10 + (float)q11[e] * w11;
                s[e] = (pl == 0) ? smp : s[e] * smp;
            }
        }
        // relu + pack to fp16 A-fragment (already in MFMA lane layout)
        f16x8 af;
#pragma unroll
        for (int e = 0; e < 8; ++e) af[e] = (_Float16)fmaxf(s[e], 0.0f);

        // MLP: h = relu(feats@W1 + b1); out = h@W2 + b2  (2 passes of 4 n-tiles)
        float sum0 = 0.f, sum1 = 0.f, sum2 = 0.f, sum3 = 0.f;
#pragma unroll
        for (int hf = 0; hf < 2; ++hf) {
            f32x4 a0 = {0.f, 0.f, 0.f, 0.f}, a1 = a0, a2 = a0, a3 = a0;
            int ntb = hf * 4;
            const f16x8* bp0 = (const f16x8*)&W1h[16 * (ntb + 0) + pl15][kb * 8];
            const f16x8* bp1 = (const f16x8*)&W1h[16 * (ntb + 1) + pl15][kb * 8];
            const f16x8* bp2 = (const f16x8*)&W1h[16 * (ntb + 2) + pl15][kb * 8];
            const f16x8* bp3 = (const f16x8*)&W1h[16 * (ntb + 3) + pl15][kb * 8];
            a0 = __builtin_amdgcn_mfma_f32_16x16x32_f16(af, *bp0, a0, 0, 0, 0);
            a1 = __builtin_amdgcn_mfma_f32_16x16x32_f16(af, *bp1, a1, 0, 0, 0);
            a2 = __builtin_amdgcn_mfma_f32_16x16x32_f16(af, *bp2, a2, 0, 0, 0);
            a3 = __builtin_amdgcn_mfma_f32_16x16x32_f16(af, *bp3, a3, 0, 0, 0);
#pragma unroll
            for (int r = 0; r < 4; ++r) {
                float h0 = fmaxf(a0[r] + b1r[ntb + 0], 0.0f);
                float h1 = fmaxf(a1[r] + b1r[ntb + 1], 0.0f);
                float h2 = fmaxf(a2[r] + b1r[ntb + 2], 0.0f);
                float h3 = fmaxf(a3[r] + b1r[ntb + 3], 0.0f);
                float v4 = h0 * w2r[ntb + 0] + h1 * w2r[ntb + 1] +
                           h2 * w2r[ntb + 2] + h3 * w2r[ntb + 3];
                if (r == 0) sum0 += v4;
                else if (r == 1) sum1 += v4;
                else if (r == 2) sum2 += v4;
                else sum3 += v4;
            }
        }
        // reduce over the 16 j-lanes (masks 1,2,4,8 stay within lane&15)
#pragma unroll
        for (int m = 1; m <= 8; m <<= 1) {
            sum0 += __shfl_xor(sum0, m, 64);
            sum1 += __shfl_xor(sum1, m, 64);
            sum2 += __shfl_xor(sum2, m, 64);
            sum3 += __shfl_xor(sum3, m, 64);
        }
        if (pl15 == 0) {                        // lanes 0,16,32,48: rows kb*4..+3
            int op = pbase + kb * 4;
            if (op + 3 < P) {
                float4 o = {sum0 + b2v, sum1 + b2v, sum2 + b2v, sum3 + b2v};
                *(float4*)(out + op) = o;       // 16B-aligned (pbase%16==0)
            } else {
                if (op + 0 < P) out[op + 0] = sum0 + b2v;
                if (op + 1 < P) out[op + 1] = sum1 + b2v;
                if (op + 2 < P) out[op + 2] = sum2 + b2v;
                if (op + 3 < P) out[op + 3] = sum3 + b2v;
            }
        }
    }
}

// ---------------------------------------------------------------------------
// Fallback (ws too small): direct CHW fp32 sampling, no workspace.
// ---------------------------------------------------------------------------
__global__ __launch_bounds__(256) void kp_direct(
    const float* __restrict__ coords,
    const float* __restrict__ p0, const float* __restrict__ p1,
    const float* __restrict__ p2,
    const float* __restrict__ W1, const float* __restrict__ b1,
    const float* __restrict__ W2, const float* __restrict__ b2,
    float* __restrict__ out, int P)
{
    __shared__ float feats[256][33];
    int t = threadIdx.x;
    int wave = t >> 6, lane = t & 63, c = lane & 31, xsel = lane >> 5;
    int pbase = blockIdx.x * 256;

    for (int i = 0; i < 64; ++i) {
        int p = pbase + i * 4 + wave;
        if (p < P) {
            float cx = coords[3 * p + 0];
            float cy = coords[3 * p + 1];
            float cz = coords[3 * p + 2];
            float f = 1.0f;
#pragma unroll
            for (int pl = 0; pl < 3; ++pl) {
                const float* plane = (pl == 0) ? p0 : ((pl == 1) ? p1 : p2);
                float u = (pl == 1) ? cy : cx;
                float v = (pl == 0) ? cy : cz;
                float xf = (u + 1.0f) * (0.5f * 511.0f);
                float yf = (v + 1.0f) * (0.5f * 511.0f);
                float x0f = floorf(xf), y0f = floorf(yf);
                float wx = xf - x0f, wy = yf - y0f;
                int x0 = min(max((int)x0f, 0), 510);
                int y0 = min(max((int)y0f, 0), 510);
                const float* bp = plane + (size_t)c * (HH * WW) +
                                  (size_t)y0 * WW + (x0 + xsel);
                float v0 = bp[0];
                float v1 = bp[WW];
                float wxl = xsel ? wx : (1.0f - wx);
                float sm = (v0 * (1.0f - wy) + v1 * wy) * wxl;
                sm += __shfl_xor(sm, 32, 64);
                f *= sm;
            }
            if (xsel == 0) feats[i * 4 + wave][c] = fmaxf(f, 0.0f);
        }
    }
    __syncthreads();
    int p = pbase + t;
    if (p < P) {
        float fr[32];
#pragma unroll
        for (int k = 0; k < 32; ++k) fr[k] = feats[t][k];
        float acc = b2[0];
#pragma unroll 4
        for (int j = 0; j < 128; ++j) {
            float a = b1[j];
#pragma unroll
            for (int k = 0; k < 32; ++k) a += fr[k] * W1[k * 128 + j];
            acc += fmaxf(a, 0.0f) * W2[j];
        }
        out[p] = acc;
    }
}

// ---------------------------------------------------------------------------
extern "C" void kernel_launch(void* const* d_in, const int* in_sizes, int n_in,
                              void* d_out, int out_size, void* d_ws, size_t ws_size,
                              hipStream_t stream) {
    const float* coords = (const float*)d_in[0];
    const float* p0 = (const float*)d_in[1];
    const float* p1 = (const float*)d_in[2];
    const float* p2 = (const float*)d_in[3];
    const float* W1 = (const float*)d_in[4];
    const float* b1 = (const float*)d_in[5];
    const float* W2 = (const float*)d_in[6];
    const float* b2 = (const float*)d_in[7];
    float* out = (float*)d_out;
    int P = in_sizes[0] / 3;   // 2,000,000

    // ws layout: [0..511] barrier | tr planes (3 x 16.8MB fp16)
    const size_t tr_off = 512;
    const size_t need   = tr_off + (size_t)3 * PLANE_H2 * sizeof(__half2);

    if (ws_size >= need) {
        int dev = 0, nCU = 0, maxb = 0;
        hipGetDevice(&dev);
        hipDeviceGetAttribute(&nCU, hipDeviceAttributeMultiprocessorCount, dev);
        hipOccupancyMaxActiveBlocksPerMultiprocessor(&maxb, kp_main, 256, 0);
        if (nCU <= 0) nCU = 32;
        if (maxb <= 0) maxb = 1;
        int nblk = nCU * maxb;

        unsigned int* bar = (unsigned int*)d_ws;
        __half2* tr = (__half2*)((char*)d_ws + tr_off);
        hipMemsetAsync(d_ws, 0, 512, stream);    // reset barrier counter (in-graph)
        kp_main<<<dim3(nblk), dim3(256), 0, stream>>>(
            coords, p0, p1, p2, W1, b1, W2, b2, out, P, bar, tr);
    } else {
        int nblk = (P + 255) / 256;
        kp_direct<<<dim3(nblk), dim3(256), 0, stream>>>(
            coords, p0, p1, p2, W1, b1, W2, b2, out, P);
    }
}

// Round 6
// 417.249 us; speedup vs baseline: 3.5049x; 1.7217x over previous
//
#include <hip/hip_runtime.h>
#include <hip/hip_fp16.h>
#include <cstdint>
#include <cstddef>

#define HH 512
#define WW 512
#define PLANE_H2 (512 * 512 * 16)     // half2 elements per transposed plane
#define PLANE_BYTES (1 << 24)         // 512*512*64B
#define NTILE (3 * 512 * 8)           // plane-transpose tile units

typedef _Float16 f16x8 __attribute__((ext_vector_type(8)));
typedef float    f32x4 __attribute__((ext_vector_type(4)));

// ---------------------------------------------------------------------------
// coords prefetch for a 16-pt group (clamped; 4B overread at P-1 is benign)
// ---------------------------------------------------------------------------
__device__ __forceinline__ float4 ldco(const float* __restrict__ coords,
                                       int g, int pl15, int P, int nG) {
    int gg = min(g, nG - 1);
    int pc = min((gg << 4) + pl15, P - 1);
    return *(const float4*)(coords + (size_t)pc * 3);
}

// issue one group's 12 corner loads (3 planes x 4 corners, 16B each)
__device__ __forceinline__ void issue_slot(const char* __restrict__ trb,
                                           float4 cc, int kb,
                                           float* wx, float* wy, f16x8* q) {
    float cx = cc.x, cy = cc.y, cz = cc.z;
#pragma unroll
    for (int pl = 0; pl < 3; ++pl) {
        float u = (pl == 1) ? cy : cx;     // -> W axis
        float v = (pl == 0) ? cy : cz;     // -> H axis
        float xf = (u + 1.0f) * (0.5f * 511.0f);
        float yf = (v + 1.0f) * (0.5f * 511.0f);
        float x0f = floorf(xf), y0f = floorf(yf);
        wx[pl] = xf - x0f;
        wy[pl] = yf - y0f;
        int x0 = min(max((int)x0f, 0), 510);
        int y0 = min(max((int)y0f, 0), 510);
        const char* bp = trb + ((size_t)pl * PLANE_BYTES) +
                         ((size_t)(y0 * WW + x0) * 64 + kb * 16);
        q[pl * 4 + 0] = *(const f16x8*)(bp);
        q[pl * 4 + 1] = *(const f16x8*)(bp + 64);
        q[pl * 4 + 2] = *(const f16x8*)(bp + WW * 64);
        q[pl * 4 + 3] = *(const f16x8*)(bp + WW * 64 + 64);
    }
}

// bilinear + product + MFMA MLP + store for one group (validated in r5)
__device__ __forceinline__ void compute_store(
    const f16x8* q, const float* wx, const float* wy,
    const _Float16* __restrict__ W1h,   // LDS [128][40]
    const float* b1r, const float* w2r, float b2v,
    float* __restrict__ out, int pbase, int P, int kb, int pl15) {
    float s[8];
#pragma unroll
    for (int pl = 0; pl < 3; ++pl) {
        float w11 = wx[pl] * wy[pl];
        float w01 = wx[pl] - w11;          // wx*(1-wy)
        float w10 = wy[pl] - w11;          // (1-wx)*wy
        float w00 = 1.0f - wx[pl] - w10;   // (1-wx)*(1-wy)
#pragma unroll
        for (int e = 0; e < 8; ++e) {
            float smp = (float)q[pl * 4 + 0][e] * w00 + (float)q[pl * 4 + 1][e] * w01 +
                        (float)q[pl * 4 + 2][e] * w10 + (float)q[pl * 4 + 3][e] * w11;
            s[e] = (pl == 0) ? smp : s[e] * smp;
        }
    }
    f16x8 af;
#pragma unroll
    for (int e = 0; e < 8; ++e) af[e] = (_Float16)fmaxf(s[e], 0.0f);

    float sum0 = 0.f, sum1 = 0.f, sum2 = 0.f, sum3 = 0.f;
#pragma unroll
    for (int hf = 0; hf < 2; ++hf) {
        f32x4 a0 = {0.f, 0.f, 0.f, 0.f}, a1 = a0, a2 = a0, a3 = a0;
        int ntb = hf * 4;
        const f16x8* bp0 = (const f16x8*)&W1h[(16 * (ntb + 0) + pl15) * 40 + kb * 8];
        const f16x8* bp1 = (const f16x8*)&W1h[(16 * (ntb + 1) + pl15) * 40 + kb * 8];
        const f16x8* bp2 = (const f16x8*)&W1h[(16 * (ntb + 2) + pl15) * 40 + kb * 8];
        const f16x8* bp3 = (const f16x8*)&W1h[(16 * (ntb + 3) + pl15) * 40 + kb * 8];
        a0 = __builtin_amdgcn_mfma_f32_16x16x32_f16(af, *bp0, a0, 0, 0, 0);
        a1 = __builtin_amdgcn_mfma_f32_16x16x32_f16(af, *bp1, a1, 0, 0, 0);
        a2 = __builtin_amdgcn_mfma_f32_16x16x32_f16(af, *bp2, a2, 0, 0, 0);
        a3 = __builtin_amdgcn_mfma_f32_16x16x32_f16(af, *bp3, a3, 0, 0, 0);
#pragma unroll
        for (int r = 0; r < 4; ++r) {
            float h0 = fmaxf(a0[r] + b1r[ntb + 0], 0.0f);
            float h1 = fmaxf(a1[r] + b1r[ntb + 1], 0.0f);
            float h2 = fmaxf(a2[r] + b1r[ntb + 2], 0.0f);
            float h3 = fmaxf(a3[r] + b1r[ntb + 3], 0.0f);
            float v4 = h0 * w2r[ntb + 0] + h1 * w2r[ntb + 1] +
                       h2 * w2r[ntb + 2] + h3 * w2r[ntb + 3];
            if (r == 0) sum0 += v4;
            else if (r == 1) sum1 += v4;
            else if (r == 2) sum2 += v4;
            else sum3 += v4;
        }
    }
#pragma unroll
    for (int m = 1; m <= 8; m <<= 1) {
        sum0 += __shfl_xor(sum0, m, 64);
        sum1 += __shfl_xor(sum1, m, 64);
        sum2 += __shfl_xor(sum2, m, 64);
        sum3 += __shfl_xor(sum3, m, 64);
    }
    if (pl15 == 0) {                        // lanes 0,16,32,48 -> rows kb*4..+3
        int op = pbase + kb * 4;
        if (op + 3 < P) {
            float4 o = {sum0 + b2v, sum1 + b2v, sum2 + b2v, sum3 + b2v};
            *(float4*)(out + op) = o;       // pbase%16==0 -> 16B aligned
        } else {
            if (op + 0 < P) out[op + 0] = sum0 + b2v;
            if (op + 1 < P) out[op + 1] = sum1 + b2v;
            if (op + 2 < P) out[op + 2] = sum2 + b2v;
            if (op + 3 < P) out[op + 3] = sum3 + b2v;
        }
    }
}

// ---------------------------------------------------------------------------
// Single-dispatch persistent kernel; phase B is a depth-2 software pipeline:
// corners for group k+1 issued before computing group k; coords prefetched
// two groups ahead. LDS: transpose tile and W1h union'd (time-disjoint).
// ---------------------------------------------------------------------------
__global__ __launch_bounds__(256, 3) void kp_main(
    const float* __restrict__ coords,
    const float* __restrict__ p0, const float* __restrict__ p1,
    const float* __restrict__ p2,
    const float* __restrict__ W1, const float* __restrict__ b1,
    const float* __restrict__ W2, const float* __restrict__ b2,
    float* __restrict__ out, int P,
    unsigned int* __restrict__ bar, __half2* __restrict__ tr)
{
    __shared__ __align__(16) char smem[10240];          // union: tileF | W1h
    float    (*tileF)[65] = (float(*)[65])smem;         // 8320 B (phase A only)
    _Float16* W1h         = (_Float16*)smem;            // [128][40] = 10240 B
    int t  = threadIdx.x;
    int nb = gridDim.x;

    // ---- phase A: planes [C,H,W] fp32 -> [H,W,C] fp16, grid-stride
    for (int bid = blockIdx.x; bid < NTILE; bid += nb) {
        int xb = bid & 7, y = (bid >> 3) & 511, pl = bid >> 12;
        const float* src = (pl == 0) ? p0 : ((pl == 1) ? p1 : p2);
        int xbase = xb * 64;
        __syncthreads();                       // tile reuse across iters
        int x = t & 63, cq = t >> 6;
#pragma unroll
        for (int i = 0; i < 8; ++i) {
            int c = cq * 8 + i;
            tileF[c][x] = src[c * (HH * WW) + y * WW + xbase + x];
        }
        __syncthreads();
        int c2 = t & 15, xq = t >> 4;
        __half2* dst = tr + (size_t)pl * PLANE_H2 + ((size_t)y * WW + xbase) * 16;
#pragma unroll
        for (int i = 0; i < 4; ++i) {
            int xx = xq * 4 + i;
            dst[xx * 16 + c2] =
                __floats2half2_rn(tileF[2 * c2][xx], tileF[2 * c2 + 1][xx]);
        }
    }
    __syncthreads();   // all tile reads done before W1h overwrites the union

    // ---- W1 -> LDS fp16 [128][40]
    for (int e = t; e < 4096; e += 256) {
        int j = e >> 5, k = e & 31;
        W1h[j * 40 + k] = (_Float16)W1[k * 128 + j];
    }

    // ---- device-wide barrier (occupancy-sized grid + timeout escape)
    __syncthreads();
    if (t == 0) {
        __threadfence();   // release tr
        __hip_atomic_fetch_add(bar, 1u, __ATOMIC_ACQ_REL, __HIP_MEMORY_SCOPE_AGENT);
        long long t0 = wall_clock64();
        while (__hip_atomic_load(bar, __ATOMIC_ACQUIRE, __HIP_MEMORY_SCOPE_AGENT)
               < (unsigned)nb) {
            __builtin_amdgcn_s_sleep(8);
            if (wall_clock64() - t0 > 50000000LL) break;   // ~0.5 s escape hatch
        }
        __threadfence();   // acquire
    }
    __syncthreads();       // also makes W1h visible block-wide

    // ---- phase B: depth-2 pipelined, barrier-free
    int wave = t >> 6, lane = t & 63;
    int pl15 = lane & 15;              // point-in-group AND j-lane AND D-col
    int kb   = lane >> 4;              // k-block / D-row group
    const char* trb = (const char*)tr;

    float b1r[8], w2r[8];
#pragma unroll
    for (int nt = 0; nt < 8; ++nt) {
        b1r[nt] = b1[16 * nt + pl15];
        w2r[nt] = W2[16 * nt + pl15];
    }
    float b2v = b2[0];

    int wid = blockIdx.x * 4 + wave;
    int nw  = nb * 4;
    int nG  = (P + 15) >> 4;

    float4 cc0 = ldco(coords, wid, pl15, P, nG);
    float4 cc1 = ldco(coords, wid + nw, pl15, P, nG);
    float wxA[3], wyA[3], wxB[3], wyB[3];
    f16x8 qA[12], qB[12];

    int g = wid;
    if (g < nG) {
        issue_slot(trb, cc0, kb, wxA, wyA, qA);   // corners for group g
        while (true) {
            // issue next group's corners (slot B), prefetch coords 2 ahead
            issue_slot(trb, cc1, kb, wxB, wyB, qB);
            cc0 = ldco(coords, g + 2 * nw, pl15, P, nG);
            compute_store(qA, wxA, wyA, W1h, b1r, w2r, b2v, out, g << 4, P, kb, pl15);
            g += nw;
            if (g >= nG) break;

            issue_slot(trb, cc0, kb, wxA, wyA, qA);
            cc1 = ldco(coords, g + 2 * nw, pl15, P, nG);
            compute_store(qB, wxB, wyB, W1h, b1r, w2r, b2v, out, g << 4, P, kb, pl15);
            g += nw;
            if (g >= nG) break;
        }
    }
}

// ---------------------------------------------------------------------------
// Fallback (ws too small): direct CHW fp32 sampling, no workspace.
// ---------------------------------------------------------------------------
__global__ __launch_bounds__(256) void kp_direct(
    const float* __restrict__ coords,
    const float* __restrict__ p0, const float* __restrict__ p1,
    const float* __restrict__ p2,
    const float* __restrict__ W1, const float* __restrict__ b1,
    const float* __restrict__ W2, const float* __restrict__ b2,
    float* __restrict__ out, int P)
{
    __shared__ float feats[256][33];
    int t = threadIdx.x;
    int wave = t >> 6, lane = t & 63, c = lane & 31, xsel = lane >> 5;
    int pbase = blockIdx.x * 256;

    for (int i = 0; i < 64; ++i) {
        int p = pbase + i * 4 + wave;
        if (p < P) {
            float cx = coords[3 * p + 0];
            float cy = coords[3 * p + 1];
            float cz = coords[3 * p + 2];
            float f = 1.0f;
#pragma unroll
            for (int pl = 0; pl < 3; ++pl) {
                const float* plane = (pl == 0) ? p0 : ((pl == 1) ? p1 : p2);
                float u = (pl == 1) ? cy : cx;
                float v = (pl == 0) ? cy : cz;
                float xf = (u + 1.0f) * (0.5f * 511.0f);
                float yf = (v + 1.0f) * (0.5f * 511.0f);
                float x0f = floorf(xf), y0f = floorf(yf);
                float wx = xf - x0f, wy = yf - y0f;
                int x0 = min(max((int)x0f, 0), 510);
                int y0 = min(max((int)y0f, 0), 510);
                const float* bp = plane + (size_t)c * (HH * WW) +
                                  (size_t)y0 * WW + (x0 + xsel);
                float v0 = bp[0];
                float v1 = bp[WW];
                float wxl = xsel ? wx : (1.0f - wx);
                float sm = (v0 * (1.0f - wy) + v1 * wy) * wxl;
                sm += __shfl_xor(sm, 32, 64);
                f *= sm;
            }
            if (xsel == 0) feats[i * 4 + wave][c] = fmaxf(f, 0.0f);
        }
    }
    __syncthreads();
    int p = pbase + t;
    if (p < P) {
        float fr[32];
#pragma unroll
        for (int k = 0; k < 32; ++k) fr[k] = feats[t][k];
        float acc = b2[0];
#pragma unroll 4
        for (int j = 0; j < 128; ++j) {
            float a = b1[j];
#pragma unroll
            for (int k = 0; k < 32; ++k) a += fr[k] * W1[k * 128 + j];
            acc += fmaxf(a, 0.0f) * W2[j];
        }
        out[p] = acc;
    }
}

// ---------------------------------------------------------------------------
extern "C" void kernel_launch(void* const* d_in, const int* in_sizes, int n_in,
                              void* d_out, int out_size, void* d_ws, size_t ws_size,
                              hipStream_t stream) {
    const float* coords = (const float*)d_in[0];
    const float* p0 = (const float*)d_in[1];
    const float* p1 = (const float*)d_in[2];
    const float* p2 = (const float*)d_in[3];
    const float* W1 = (const float*)d_in[4];
    const float* b1 = (const float*)d_in[5];
    const float* W2 = (const float*)d_in[6];
    const float* b2 = (const float*)d_in[7];
    float* out = (float*)d_out;
    int P = in_sizes[0] / 3;   // 2,000,000

    // ws layout: [0..511] barrier | tr planes (3 x 16.8MB fp16)
    const size_t tr_off = 512;
    const size_t need   = tr_off + (size_t)3 * PLANE_H2 * sizeof(__half2);

    if (ws_size >= need) {
        int dev = 0, nCU = 0, maxb = 0;
        hipGetDevice(&dev);
        hipDeviceGetAttribute(&nCU, hipDeviceAttributeMultiprocessorCount, dev);
        hipOccupancyMaxActiveBlocksPerMultiprocessor(&maxb, kp_main, 256, 0);
        if (nCU <= 0) nCU = 32;
        if (maxb <= 0) maxb = 1;
        int nblk = nCU * maxb;

        unsigned int* bar = (unsigned int*)d_ws;
        __half2* tr = (__half2*)((char*)d_ws + tr_off);
        hipMemsetAsync(d_ws, 0, 512, stream);    // reset barrier counter (in-graph)
        kp_main<<<dim3(nblk), dim3(256), 0, stream>>>(
            coords, p0, p1, p2, W1, b1, W2, b2, out, P, bar, tr);
    } else {
        int nblk = (P + 255) / 256;
        kp_direct<<<dim3(nblk), dim3(256), 0, stream>>>(
            coords, p0, p1, p2, W1, b1, W2, b2, out, P);
    }
}